// Round 3
// baseline (178.771 us; speedup 1.0000x reference)
//
#include <hip/hip_runtime.h>
#include <hip/hip_fp16.h>

#define GSZ 640
#define NIMG 320
#define MS 102400
#define NC 12
#define BETA_F 13.8551004f
#define TWOPI_F 6.2831855f
// fp16 grid scaling: G is ~1e-9..1e-10 in the reference's un-normalized KB
// convention. Scale by 2^24 ONCE in passA; fold 2^-24 into the tap weights.
#define GSC 16777216.0f
#define GSC_INV 5.9604645e-8f

// binning / tiling
#define TEDGE 16
#define NT1 40            // 640/16
#define NTILES 1600       // 40*40
#define PAT 21            // TEDGE + 5 (tap window is 6 wide, base offset -2..+3)
#define PROW 252          // PAT*12 uints per patch row
#define GPAD 645          // 640 + 5 halo (pad coord = true + 2)
#define NSMAX 128         // samples per chunk in interp (mean/tile = 64)

// ---------- Bessel I0 (Abramowitz & Stegun 9.8.1 / 9.8.2, rel err < 2e-7) ----------
__device__ __forceinline__ float i0f(float x) {
    float ax = fabsf(x);
    if (ax < 3.75f) {
        float t = ax * (1.0f / 3.75f);
        t *= t;
        return 1.0f + t * (3.5156229f + t * (3.0899424f + t * (1.2067492f +
                     t * (0.2659732f + t * (0.0360768f + t * 0.0045813f)))));
    } else {
        float t = 3.75f / ax;
        float p = 0.39894228f + t * (0.01328592f + t * (0.00225319f + t * (-0.00157565f +
                  t * (0.00916281f + t * (-0.02057706f + t * (0.02635537f +
                  t * (-0.01647633f + t * 0.00392377f)))))));
        return p * __expf(ax) * rsqrtf(ax);
    }
}

// Kaiser-Bessel kernel, support |u| <= 3 (J=6)
__device__ __forceinline__ float kbval(float u) {
    float mm = fabsf(u) * (1.0f / 3.0f);
    float s = 1.0f - mm * mm;
    s = s > 0.0f ? s : 0.0f;
    float v = i0f(BETA_F * sqrtf(s)) * (1.0f / 6.0f);
    return (mm <= 1.0f) ? v : 0.0f;
}

// base grid index (wrapped to [0,640)) + frac for one k-coordinate.
// Weights are kbval(frac + 2 - j); taps are ib-2 .. ib+3 (periodic).
__device__ __forceinline__ int tapbase(float om, float* frac) {
    float t = fmodf((om * 640.0f) / TWOPI_F, 640.0f);
    if (t < 0.0f) t += 640.0f;
    float b = floorf(t);
    *frac = t - b;
    int ib = (int)b;
    if (ib >= GSZ) ib -= GSZ;   // t == 640.0 edge; frac=0 so weights consistent
    return ib;
}

__device__ __forceinline__ float2 cmul(float2 a, float2 w) {
    return make_float2(a.x * w.x - a.y * w.y, a.x * w.y + a.y * w.x);
}

// Stockham DIF radix-4 stage with LDS twiddle table. 160 butterflies, t < 160.
__device__ __forceinline__ void radix4_stage(const float2* src, float2* dst,
                                             const float2* tw, int t, int s,
                                             int n, int mult) {
    int p = t / s, q = t - p * s;
    int m = n >> 2;
    float2 a0 = src[q + s * p];
    float2 a1 = src[q + s * (p + m)];
    float2 a2 = src[q + s * (p + 2 * m)];
    float2 a3 = src[q + s * (p + 3 * m)];
    float2 e = make_float2(a0.x + a2.x, a0.y + a2.y);
    float2 f = make_float2(a1.x + a3.x, a1.y + a3.y);
    float2 g = make_float2(a0.x - a2.x, a0.y - a2.y);
    float2 h = make_float2(a1.x - a3.x, a1.y - a3.y);
    float2 B0 = make_float2(e.x + f.x, e.y + f.y);
    float2 B2 = make_float2(e.x - f.x, e.y - f.y);
    float2 mih = make_float2(h.y, -h.x);                 // -i*h
    float2 B1 = make_float2(g.x + mih.x, g.y + mih.y);
    float2 B3 = make_float2(g.x - mih.x, g.y - mih.y);
    int pm = p * mult;
    dst[q + s * (4 * p)]     = B0;
    dst[q + s * (4 * p + 1)] = cmul(B1, tw[pm]);
    dst[q + s * (4 * p + 2)] = cmul(B2, tw[2 * pm]);
    dst[q + s * (4 * p + 3)] = cmul(B3, tw[3 * pm]);
}

// ---------- 640-point FFT: radix-5, 3x radix-4 (LDS), final radix-2 in regs ----------
__device__ void fft640(float2* bA, float2* bB, const float2* tw, int t,
                       float2* olo, float2* ohi) {
    __syncthreads();   // bA + tw ready
    if (t < 128) {
        float2 aj[5];
        #pragma unroll
        for (int j = 0; j < 5; ++j) aj[j] = bA[t + 128 * j];
        const float wr[5] = {1.0f, 0.30901699f, -0.80901699f, -0.80901699f, 0.30901699f};
        const float wi[5] = {0.0f, -0.95105652f, -0.58778525f, 0.58778525f, 0.95105652f};
        #pragma unroll
        for (int r = 0; r < 5; ++r) {
            float br = aj[0].x, bi = aj[0].y;
            #pragma unroll
            for (int j = 1; j < 5; ++j) {
                int k = (j * r) % 5;
                br += aj[j].x * wr[k] - aj[j].y * wi[k];
                bi += aj[j].x * wi[k] + aj[j].y * wr[k];
            }
            bB[5 * t + r] = cmul(make_float2(br, bi), tw[t * r]);  // idx <= 508
        }
    }
    __syncthreads();
    if (t < 160) radix4_stage(bB, bA, tw, t, 5, 128, 5);
    __syncthreads();
    if (t < 160) radix4_stage(bA, bB, tw, t, 20, 32, 20);
    __syncthreads();
    if (t < 160) radix4_stage(bB, bA, tw, t, 80, 8, 80);
    __syncthreads();
    float2 a = bA[t], b = bA[t + 320];
    *olo = make_float2(a.x + b.x, a.y + b.y);
    *ohi = make_float2(a.x - b.x, a.y - b.y);
}

// ---------- pass A: row FFT, 2 rows/block; apod in LDS; also zeroes bin counts ----
__global__ __launch_bounds__(640)
void passA_kernel(const float* __restrict__ img_r, const float* __restrict__ img_i,
                  const float* __restrict__ sm_r, const float* __restrict__ sm_i,
                  unsigned int* __restrict__ R16, int* __restrict__ cnt) {
    __shared__ float2 bA[2][GSZ], bB[2][GSZ], tw[GSZ];
    __shared__ float apodS[NIMG];
    if (blockIdx.y == 0 && blockIdx.x < 3) {        // zero bin counters (stream-ordered
        int z = blockIdx.x * 640 + threadIdx.x;     //  before bincount_kernel)
        if (z < NTILES) cnt[z] = 0;
    }
    {
        float sn, cs;
        __sincosf((-TWOPI_F / 640.0f) * (float)threadIdx.x, &sn, &cs);
        tw[threadIdx.x] = make_float2(cs, sn);
    }
    if (threadIdx.x < NIMG) {
        int n = threadIdx.x;
        float s = 0.0f;
        #pragma unroll
        for (int j = -3; j <= 3; ++j)
            s += kbval((float)j) * __cosf((TWOPI_F * (float)j * ((float)n - 160.0f)) / 640.0f);
        apodS[n] = 1.0f / s;
    }
    __syncthreads();   // apodS ready
    int e = threadIdx.x >= 320;
    int t = threadIdx.x - 320 * e;
    int ri = 2 * blockIdx.x + e, c = blockIdx.y;
    int h = (ri < 160) ? ri + 160 : ri - 160;
    int w = (t < 160) ? t + 160 : t - 160;
    float scale = apodS[h] * apodS[w] * (GSC / 640.0f);
    float xr = img_r[h * NIMG + w];
    float xi = img_i[h * NIMG + w];
    float sr = sm_r[(c * NIMG + h) * NIMG + w];
    float si = sm_i[(c * NIMG + h) * NIMG + w];
    float vr = (xr * sr - xi * si) * scale;
    float vi = (xr * si + xi * sr) * scale;
    int vnz = (t < 160) ? t : t + 320;   // ifftshifted column position
    int vz  = (t < 160) ? t + 320 : t;
    bA[e][vnz] = make_float2(vr, vi);
    bA[e][vz]  = make_float2(0.0f, 0.0f);
    float2 lo, hi;
    fft640(bA[e], bB[e], tw, t, &lo, &hi);
    __half2 hlo = __float22half2_rn(lo);
    __half2 hhi = __float22half2_rn(hi);
    unsigned int* out = R16 + (c * 320 + ri) * GSZ;
    out[t]       = *(const unsigned int*)&hlo;
    out[t + 320] = *(const unsigned int*)&hhi;
}

// ---------- binning: count -> scan -> scatter ----------
__global__ __launch_bounds__(256)
void bincount_kernel(const float* __restrict__ kt, int* __restrict__ cnt) {
    int m = blockIdx.x * 256 + threadIdx.x;     // 400*256 == MS
    float f;
    int ibu = tapbase(kt[m], &f);               // u axis (om[0])
    int ibq = tapbase(kt[MS + m], &f);          // q axis (om[1])
    atomicAdd(&cnt[(ibq >> 4) * NT1 + (ibu >> 4)], 1);
}

__global__ __launch_bounds__(256)
void scan_kernel(const int* __restrict__ cnt, int* __restrict__ offs) {
    __shared__ int sp[256];
    int t = threadIdx.x;
    int c7[7];
    int psum = 0;
    #pragma unroll
    for (int k = 0; k < 7; ++k) {               // 256*7 = 1792 >= 1600
        int i = t * 7 + k;
        int v = (i < NTILES) ? cnt[i] : 0;
        c7[k] = v;
        psum += v;
    }
    sp[t] = psum;
    __syncthreads();
    for (int off = 1; off < 256; off <<= 1) {   // Hillis-Steele inclusive
        int v = (t >= off) ? sp[t - off] : 0;
        __syncthreads();
        sp[t] += v;
        __syncthreads();
    }
    int run = (t == 0) ? 0 : sp[t - 1];         // exclusive base
    #pragma unroll
    for (int k = 0; k < 7; ++k) {
        int i = t * 7 + k;
        if (i < NTILES) offs[i] = run;
        run += c7[k];
    }
}

__global__ __launch_bounds__(256)
void binscatter_kernel(const float* __restrict__ kt, int* __restrict__ offs,
                       int* __restrict__ order) {
    int m = blockIdx.x * 256 + threadIdx.x;
    float f;
    int ibu = tapbase(kt[m], &f);
    int ibq = tapbase(kt[MS + m], &f);
    int pos = atomicAdd(&offs[(ibq >> 4) * NT1 + (ibu >> 4)], 1);
    order[pos] = m;       // offs[tile] ends at start+cnt; interp derives start = end-cnt
}

// ---------- pass B1G: column FFT, one (q, coil-quad) per block; writes halo-padded
// Gpad[qp][up][c] uint (half2 per coil), pad coord = true + 2; edge rows/cols
// duplicated so interp tiles never wrap (<=4 stores per thread, most do 1).
__global__ __launch_bounds__(640)
void passB1G_kernel(const unsigned int* __restrict__ R16, unsigned int* __restrict__ Gpad) {
    __shared__ float2 bA[2][GSZ], bB[2][GSZ], tw[GSZ];
    __shared__ unsigned int Gs[4][GSZ + 1];
    {
        float sn, cs;
        __sincosf((-TWOPI_F / 640.0f) * (float)threadIdx.x, &sn, &cs);
        tw[threadIdx.x] = make_float2(cs, sn);
    }
    // XCD-bijective swizzle on q: 640 = 8*80; consecutive q share R16 cache lines.
    int q = ((int)blockIdx.x % 8) * 80 + (int)blockIdx.x / 8;
    int p = blockIdx.y;                 // coil quad 0..2
    int e = threadIdx.x >= 320;
    int t = threadIdx.x - 320 * e;
    int rnz = (t < 160) ? t : t + 320;
    int rz  = (t < 160) ? t + 320 : t;
    for (int cp = 0; cp < 2; ++cp) {
        int c = 4 * p + 2 * cp + e;
        unsigned int raw = R16[(c * 320 + t) * GSZ + q];   // strided gather, L2/L3 hit
        bA[e][rnz] = __half22float2(*(const __half2*)&raw);
        bA[e][rz]  = make_float2(0.0f, 0.0f);
        float2 lo, hi;
        fft640(bA[e], bB[e], tw, t, &lo, &hi);
        __half2 hlo = __float22half2_rn(lo);
        __half2 hhi = __float22half2_rn(hi);
        Gs[2 * cp + e][t]       = *(const unsigned int*)&hlo;
        Gs[2 * cp + e][t + 320] = *(const unsigned int*)&hhi;
    }
    __syncthreads();   // all 4 coils stashed
    int u = threadIdx.x;
    uint4 gq;
    gq.x = Gs[0][u]; gq.y = Gs[1][u]; gq.z = Gs[2][u]; gq.w = Gs[3][u];
    int qp[2], up[2];
    int nq = 1, nu = 1;
    qp[0] = q + 2;
    if (q < 3) qp[nq++] = q + 642;          // true 0..2 also at pad 642..644
    else if (q >= 638) qp[nq++] = q - 638;  // true 638,639 also at pad 0,1
    up[0] = u + 2;
    if (u < 3) up[nu++] = u + 642;
    else if (u >= 638) up[nu++] = u - 638;
    for (int a = 0; a < nq; ++a)
        for (int b = 0; b < nu; ++b)
            *(uint4*)&Gpad[((size_t)qp[a] * GPAD + up[b]) * 12 + 4 * p] = gq;
}

// ---------- tiled interpolation: stage (16+5)^2 patch in LDS, gather locally ------
__global__ __launch_bounds__(256)
void interp_tiled_kernel(const float* __restrict__ kt,
                         const unsigned int* __restrict__ Gpad,
                         const int* __restrict__ cnt, const int* __restrict__ offs,
                         const int* __restrict__ order, float2* __restrict__ out) {
    __shared__ __align__(16) unsigned int patch[PAT * PROW];   // 21.2 KB
    __shared__ float tw1s[NSMAX][6], tw2s[NSMAX][6];
    __shared__ int tslm[NSMAX];
    int tile = blockIdx.x;
    int TQ = tile / NT1, TU = tile - TQ * NT1;
    {   // stage: 21 rows x 63 uint4, fully coalesced
        const uint4* g4 = (const uint4*)Gpad;
        uint4* p4 = (uint4*)patch;
        int base = (TQ * TEDGE * GPAD + TU * TEDGE) * 3;   // uint4 index of patch row 0
        for (int i = threadIdx.x; i < PAT * 63; i += 256) {
            int r = i / 63, c = i - r * 63;
            p4[i] = g4[base + r * (GPAD * 3) + c];
        }
    }
    int end = offs[tile], ns = cnt[tile], start = end - ns;
    for (int s0 = 0; s0 < ns; s0 += NSMAX) {
        int nss = min(NSMAX, ns - s0);
        if ((int)threadIdx.x < nss) {           // taps once per sample
            int m = order[start + s0 + threadIdx.x];
            float fu, fq;
            int ibu = tapbase(kt[m], &fu);
            int ibq = tapbase(kt[MS + m], &fq);
            #pragma unroll
            for (int j = 0; j < 6; ++j) {
                tw1s[threadIdx.x][j] = kbval(fu + (float)(2 - j));
                tw2s[threadIdx.x][j] = kbval(fq + (float)(2 - j)) * GSC_INV;
            }
            tslm[threadIdx.x] = (m << 8) | ((ibu & 15) << 4) | (ibq & 15);
        }
        __syncthreads();                        // patch + taps ready
        for (int it = threadIdx.x; it < 3 * nss; it += 256) {
            int s = it / 3;
            int p = it - 3 * s;                 // coil quad 0..2
            int pk = tslm[s];
            int slq = pk & 15, slu = (pk >> 4) & 15, m = pk >> 8;
            float ar[4] = {0.f, 0.f, 0.f, 0.f}, ai[4] = {0.f, 0.f, 0.f, 0.f};
            #pragma unroll
            for (int j2 = 0; j2 < 6; ++j2) {
                int rowoff = (slq + j2) * PROW + slu * 12 + 4 * p;
                float b2 = tw2s[s][j2];
                #pragma unroll
                for (int j1 = 0; j1 < 6; ++j1) {
                    float4 gq = *(const float4*)&patch[rowoff + j1 * 12];
                    const __half2* h = (const __half2*)&gq;   // 4 x (re,im)
                    float ww = b2 * tw1s[s][j1];
                    #pragma unroll
                    for (int k = 0; k < 4; ++k) {
                        float2 fv = __half22float2(h[k]);
                        ar[k] = fmaf(ww, fv.x, ar[k]);
                        ai[k] = fmaf(ww, fv.y, ai[k]);
                    }
                }
            }
            #pragma unroll
            for (int k = 0; k < 4; ++k)
                out[(4 * p + k) * MS + m] = make_float2(ar[k], ai[k]);
        }
        __syncthreads();                        // before next chunk's tap overwrite
    }
}

extern "C" void kernel_launch(void* const* d_in, const int* in_sizes, int n_in,
                              void* d_out, int out_size, void* d_ws, size_t ws_size,
                              hipStream_t stream) {
    const float* img_r = (const float*)d_in[0];
    const float* img_i = (const float*)d_in[1];
    const float* sm_r  = (const float*)d_in[2];
    const float* sm_i  = (const float*)d_in[3];
    const float* kt    = (const float*)d_in[4];

    // ws layout (~30.2MB): [R16 9.83M][Gpad 19.97M][cnt 6.4K][offs 6.4K][order 0.41M]
    char* base = (char*)d_ws;
    unsigned int* R16  = (unsigned int*)base;                   // 12*320*640*4
    unsigned int* Gpad = (unsigned int*)(base + 9830400);       // 645*645*12*4
    int* cnt           = (int*)(base + 29799600);
    int* offs          = (int*)(base + 29806000);
    int* order         = (int*)(base + 29812400);

    passA_kernel<<<dim3(160, NC), 640, 0, stream>>>(img_r, img_i, sm_r, sm_i, R16, cnt);
    bincount_kernel<<<400, 256, 0, stream>>>(kt, cnt);
    scan_kernel<<<1, 256, 0, stream>>>(cnt, offs);
    binscatter_kernel<<<400, 256, 0, stream>>>(kt, offs, order);
    passB1G_kernel<<<dim3(GSZ, 3), 640, 0, stream>>>(R16, Gpad);
    interp_tiled_kernel<<<NTILES, 256, 0, stream>>>(kt, Gpad, cnt, offs, order, (float2*)d_out);
}

// Round 4
// 164.374 us; speedup vs baseline: 1.0876x; 1.0876x over previous
//
#include <hip/hip_runtime.h>
#include <hip/hip_fp16.h>

#define GSZ 640
#define NIMG 320
#define MS 102400
#define NC 12
#define BETA_F 13.8551004f
#define TWOPI_F 6.2831855f
// fp16 grid scaling: G is ~1e-9..1e-10 in the reference's un-normalized KB
// convention. Scale by 2^24 ONCE in passA; fold 2^-24 into the tap weights.
#define GSC 16777216.0f
#define GSC_INV 5.9604645e-8f

// binning / tiling
#define TEDGE 16
#define NT1 40            // 640/16
#define NTILES 1600       // 40*40
#define PAT 21            // TEDGE + 5 (tap window is 6 wide, base offset -2..+3)
#define PROW 252          // PAT*12 uints per patch row
#define GPAD 645          // 640 + 5 halo (pad coord = true + 2)
#define NSMAX 128         // samples per chunk in interp (mean/tile = 64)

// ---------- Bessel I0 (Abramowitz & Stegun 9.8.1 / 9.8.2, rel err < 2e-7) ----------
__device__ __forceinline__ float i0f(float x) {
    float ax = fabsf(x);
    if (ax < 3.75f) {
        float t = ax * (1.0f / 3.75f);
        t *= t;
        return 1.0f + t * (3.5156229f + t * (3.0899424f + t * (1.2067492f +
                     t * (0.2659732f + t * (0.0360768f + t * 0.0045813f)))));
    } else {
        float t = 3.75f / ax;
        float p = 0.39894228f + t * (0.01328592f + t * (0.00225319f + t * (-0.00157565f +
                  t * (0.00916281f + t * (-0.02057706f + t * (0.02635537f +
                  t * (-0.01647633f + t * 0.00392377f)))))));
        return p * __expf(ax) * rsqrtf(ax);
    }
}

// Kaiser-Bessel kernel, support |u| <= 3 (J=6)
__device__ __forceinline__ float kbval(float u) {
    float mm = fabsf(u) * (1.0f / 3.0f);
    float s = 1.0f - mm * mm;
    s = s > 0.0f ? s : 0.0f;
    float v = i0f(BETA_F * sqrtf(s)) * (1.0f / 6.0f);
    return (mm <= 1.0f) ? v : 0.0f;
}

// base grid index (wrapped to [0,640)) + frac for one k-coordinate.
__device__ __forceinline__ int tapbase(float om, float* frac) {
    float t = fmodf((om * 640.0f) / TWOPI_F, 640.0f);
    if (t < 0.0f) t += 640.0f;
    float b = floorf(t);
    *frac = t - b;
    int ib = (int)b;
    if (ib >= GSZ) ib -= GSZ;
    return ib;
}

__device__ __forceinline__ float2 cmul(float2 a, float2 w) {
    return make_float2(a.x * w.x - a.y * w.y, a.x * w.y + a.y * w.x);
}

// =====================================================================
// Wave-level 640-point FFT (barrier-free).
// Decompose n = n1 + 64*n2 (n1 = lane 0..63, n2 = reg 0..9),
//           k = k2 + 10*k1 (k2 = reg, k1 = cross-lane index).
// X[k2+10*k1] = sum_n1 W64^{n1*k1} * W640^{n1*k2} * (DFT10 of lane n1's regs)[k2]
// Cross-lane 64-pt FFT: 6 radix-2 DIF shuffle stages; output k1 = bitrev6(lane).
// Per-lane constants (computed ONCE per kernel):
//   t640[k] = W640^{lane*k}; t64[m] = W64^{(lane & (32>>m - 1)) << m}; br = bitrev6(lane)
// =====================================================================
__device__ __forceinline__ void wf_init(int lane, float2* t64, float2* t640, int* br) {
    #pragma unroll
    for (int m = 0; m < 6; ++m) {
        int mask = 32 >> m;
        float e = (float)((lane & (mask - 1)) << m);
        float sn, cs;
        __sincosf((-TWOPI_F / 64.0f) * e, &sn, &cs);
        t64[m] = make_float2(cs, sn);
    }
    float sn, cs;
    __sincosf((-TWOPI_F / 640.0f) * (float)lane, &sn, &cs);
    float2 w1 = make_float2(cs, sn);
    t640[0] = make_float2(1.0f, 0.0f);
    #pragma unroll
    for (int k = 1; k < 10; ++k) t640[k] = cmul(t640[k - 1], w1);
    *br = (int)(__brev((unsigned int)lane) >> 26);
}

// DFT-10 via even/odd split into two DFT-5s: Y[k] = E[k%5] + W10^k * O[k%5]
__device__ __forceinline__ void dft10(const float2* v, float2* y) {
    const float wr5[5] = {1.0f, 0.30901699f, -0.80901699f, -0.80901699f, 0.30901699f};
    const float wi5[5] = {0.0f, -0.95105652f, -0.58778525f, 0.58778525f, 0.95105652f};
    float2 E[5], O[5];
    #pragma unroll
    for (int r = 0; r < 5; ++r) {
        float er = v[0].x, ei = v[0].y;
        float os = v[1].x, oi = v[1].y;
        #pragma unroll
        for (int c = 1; c < 5; ++c) {
            int k = (r * c) % 5;
            er += v[2 * c].x * wr5[k] - v[2 * c].y * wi5[k];
            ei += v[2 * c].x * wi5[k] + v[2 * c].y * wr5[k];
            os += v[2 * c + 1].x * wr5[k] - v[2 * c + 1].y * wi5[k];
            oi += v[2 * c + 1].x * wi5[k] + v[2 * c + 1].y * wr5[k];
        }
        E[r] = make_float2(er, ei);
        O[r] = make_float2(os, oi);
    }
    const float wr10[10] = {1.0f, 0.80901699f, 0.30901699f, -0.30901699f, -0.80901699f,
                            -1.0f, -0.80901699f, -0.30901699f, 0.30901699f, 0.80901699f};
    const float wi10[10] = {0.0f, -0.58778525f, -0.95105652f, -0.95105652f, -0.58778525f,
                            0.0f, 0.58778525f, 0.95105652f, 0.95105652f, 0.58778525f};
    #pragma unroll
    for (int k = 0; k < 10; ++k) {
        int r = k % 5;
        float2 t = cmul(O[r], make_float2(wr10[k], wi10[k]));
        y[k] = make_float2(E[r].x + t.x, E[r].y + t.y);
    }
}

// in: v[j] = x[lane + 64*j]; out: v[k2] = X[k2 + 10*bitrev6(lane)]
__device__ __forceinline__ void wfft640(float2* v, const float2* t640, const float2* t64,
                                        int lane) {
    float2 y[10];
    dft10(v, y);
    #pragma unroll
    for (int k = 1; k < 10; ++k) y[k] = cmul(y[k], t640[k]);
    #pragma unroll
    for (int m = 0; m < 6; ++m) {
        int mask = 32 >> m;
        bool up = (lane & mask) != 0;
        float2 tw = t64[m];
        #pragma unroll
        for (int k = 0; k < 10; ++k) {
            float2 a = y[k];
            float2 b;
            b.x = __shfl_xor(a.x, mask, 64);
            b.y = __shfl_xor(a.y, mask, 64);
            // low lane: a+b ; high lane: (b-a)*tw  (b = partner = low value)
            float2 d = make_float2(b.x - a.x, b.y - a.y);
            float2 cm = cmul(d, tw);
            y[k] = up ? cm : make_float2(a.x + b.x, a.y + b.y);
        }
    }
    #pragma unroll
    for (int k = 0; k < 10; ++k) v[k] = y[k];
}

// ---------- block-0 inline scan (1600 tile counts -> exclusive offsets) ----------
__device__ void scan_inline(const int* __restrict__ cnt, int* __restrict__ offs, int* sp) {
    int t = threadIdx.x;
    int c7[7];
    int psum = 0;
    if (t < 256) {
        #pragma unroll
        for (int k = 0; k < 7; ++k) {
            int i = t * 7 + k;
            int v = (i < NTILES) ? cnt[i] : 0;
            c7[k] = v;
            psum += v;
        }
        sp[t] = psum;
    }
    __syncthreads();
    for (int off = 1; off < 256; off <<= 1) {
        int v = (t >= off && t < 256) ? sp[t - off] : 0;
        __syncthreads();
        if (t < 256) sp[t] += v;
        __syncthreads();
    }
    if (t < 256) {
        int run = (t == 0) ? 0 : sp[t - 1];
        #pragma unroll
        for (int k = 0; k < 7; ++k) {
            int i = t * 7 + k;
            if (i < NTILES) offs[i] = run;
            run += c7[k];
        }
    }
}

// ---------- pass A: 8 waves/block, one row-FFT per wave; + bincount fold-in ------
// Padded-row element p = lane + 64*j: p<160 -> img col p+160 ; p>=480 -> col p-480.
__global__ __launch_bounds__(512)
void passA_kernel(const float* __restrict__ img_r, const float* __restrict__ img_i,
                  const float* __restrict__ sm_r, const float* __restrict__ sm_i,
                  const float* __restrict__ kt, int* __restrict__ cnt,
                  unsigned int* __restrict__ R16) {
    __shared__ unsigned int Rs[8][GSZ];
    __shared__ float apodS[NIMG];
    int gid = blockIdx.x * 512 + threadIdx.x;
    if (gid < MS) {                              // fused bincount (cnt pre-zeroed)
        float f;
        int ibu = tapbase(kt[gid], &f);
        int ibq = tapbase(kt[MS + gid], &f);
        atomicAdd(&cnt[(ibq >> 4) * NT1 + (ibu >> 4)], 1);
    }
    if (threadIdx.x < NIMG) {
        int n = threadIdx.x;
        float s = 0.0f;
        #pragma unroll
        for (int j = -3; j <= 3; ++j)
            s += kbval((float)j) * __cosf((TWOPI_F * (float)j * ((float)n - 160.0f)) / 640.0f);
        apodS[n] = 1.0f / s;
    }
    int lane = threadIdx.x & 63;
    int wv = threadIdx.x >> 6;
    float2 t64[6], t640[10];
    int br;
    wf_init(lane, t64, t640, &br);
    __syncthreads();                             // apodS ready
    int id = blockIdx.x * 8 + wv;                // 480*8 == 3840 == 12*320
    int c = id / 320, ri = id - 320 * c;
    int h = (ri < 160) ? ri + 160 : ri - 160;    // row ifftshift
    const float* ir = img_r + h * NIMG;
    const float* ii = img_i + h * NIMG;
    const float* smr = sm_r + (c * NIMG + h) * NIMG;
    const float* smi = sm_i + (c * NIMG + h) * NIMG;
    float ah = apodS[h] * (GSC / 640.0f);
    auto ld = [&](int wc) {
        float xr = ir[wc], xi = ii[wc];
        float sr = smr[wc], si = smi[wc];
        float sc = ah * apodS[wc];
        return make_float2((xr * sr - xi * si) * sc, (xr * si + xi * sr) * sc);
    };
    const float2 z2 = make_float2(0.0f, 0.0f);
    float2 v[10];
    v[0] = ld(lane + 160);                       // p in [0,64)
    v[1] = ld(lane + 224);                       // p in [64,128)
    { float2 tv = ld((lane < 32) ? lane + 288 : 0); v[2] = (lane < 32) ? tv : z2; }
    v[3] = z2; v[4] = z2; v[5] = z2; v[6] = z2;
    { float2 tv = ld((lane >= 32) ? lane - 32 : 0); v[7] = (lane >= 32) ? tv : z2; }
    v[8] = ld(lane + 32);                        // p in [512,576)
    v[9] = ld(lane + 96);                        // p in [576,640)
    wfft640(v, t640, t64, lane);
    unsigned int* rs = Rs[wv];                   // wave-private: no barrier needed
    #pragma unroll
    for (int k = 0; k < 10; ++k) {
        __half2 hv = __float22half2_rn(v[k]);
        rs[10 * br + k] = *(const unsigned int*)&hv;
    }
    unsigned int* outp = R16 + (c * 320 + ri) * GSZ;
    #pragma unroll
    for (int j = 0; j < 10; ++j)
        outp[lane + 64 * j] = rs[lane + 64 * j]; // coalesced row write
}

// ---------- pass B1G: one q per block, 12 coil column-FFTs over 8 waves ----------
// Assemble [u][c] row in LDS (pad 13), then write the WHOLE padded Gpad row
// contiguously (fixes R3's stride-48B scattered halo store). Block 0 also runs
// the bin scan (launch boundary gives cnt-complete).
__global__ __launch_bounds__(512)
void passB1G_kernel(const unsigned int* __restrict__ R16, const int* __restrict__ cnt,
                    int* __restrict__ offs, unsigned int* __restrict__ Gpad) {
    __shared__ unsigned int Gs[GSZ * 13];
    __shared__ int sp[256];
    if (blockIdx.x == 0) scan_inline(cnt, offs, sp);
    int lane = threadIdx.x & 63;
    int wv = threadIdx.x >> 6;
    float2 t64[6], t640[10];
    int br;
    wf_init(lane, t64, t640, &br);
    // XCD swizzle: 640 = 8*80, consecutive q (sharing R16 lines) stay on one XCD.
    int q = ((int)blockIdx.x & 7) * 80 + ((int)blockIdx.x >> 3);
    const float2 z2 = make_float2(0.0f, 0.0f);
    for (int c = wv; c < NC; c += 8) {
        const unsigned int* col = R16 + (size_t)c * 320 * GSZ + q;
        auto ld = [&](int t) {
            unsigned int raw = col[(size_t)t * GSZ];
            return __half22float2(*(const __half2*)&raw);
        };
        float2 v[10];
        v[0] = ld(lane);                          // t = p
        v[1] = ld(lane + 64);
        { float2 tv = ld(lane + 128);             // t in [128,192): j=2 (p<160) / j=7 (p>=480)
          v[2] = (lane < 32) ? tv : z2;
          v[7] = (lane < 32) ? z2 : tv; }
        v[3] = z2; v[4] = z2; v[5] = z2; v[6] = z2;
        v[8] = ld(lane + 192);                    // t = p-320
        v[9] = ld(lane + 256);
        wfft640(v, t640, t64, lane);
        #pragma unroll
        for (int k = 0; k < 10; ++k) {
            __half2 hv = __float22half2_rn(v[k]);
            Gs[(10 * br + k) * 13 + c] = *(const unsigned int*)&hv;   // u = 10*br+k
        }
    }
    __syncthreads();                              // all 12 coils stashed
    size_t rowbase = (size_t)(q + 2) * (GPAD * 12);
    for (int idx = threadIdx.x; idx < GPAD * 12; idx += 512) {
        int up = idx / 12, cc = idx - up * 12;
        int u = (up < 2) ? up + 638 : ((up < 642) ? up - 2 : up - 642);
        Gpad[rowbase + idx] = Gs[u * 13 + cc];    // contiguous padded row
    }
    int qp2 = (q < 3) ? q + 642 : ((q >= 638) ? q - 638 : -1);
    if (qp2 >= 0) {                               // q-halo duplicate rows
        size_t rb2 = (size_t)qp2 * (GPAD * 12);
        for (int idx = threadIdx.x; idx < GPAD * 12; idx += 512) {
            int up = idx / 12, cc = idx - up * 12;
            int u = (up < 2) ? up + 638 : ((up < 642) ? up - 2 : up - 642);
            Gpad[rb2 + idx] = Gs[u * 13 + cc];
        }
    }
}

// ---------- bin scatter (after scan) ----------
__global__ __launch_bounds__(256)
void binscatter_kernel(const float* __restrict__ kt, int* __restrict__ offs,
                       int* __restrict__ order) {
    int m = blockIdx.x * 256 + threadIdx.x;
    float f;
    int ibu = tapbase(kt[m], &f);
    int ibq = tapbase(kt[MS + m], &f);
    int pos = atomicAdd(&offs[(ibq >> 4) * NT1 + (ibu >> 4)], 1);
    order[pos] = m;       // offs[tile] ends at start+cnt; interp derives start = end-cnt
}

// ---------- tiled interpolation: stage (16+5)^2 patch in LDS, gather locally ------
__global__ __launch_bounds__(256)
void interp_tiled_kernel(const float* __restrict__ kt,
                         const unsigned int* __restrict__ Gpad,
                         const int* __restrict__ cnt, const int* __restrict__ offs,
                         const int* __restrict__ order, float2* __restrict__ out) {
    __shared__ __align__(16) unsigned int patch[PAT * PROW];   // 21.2 KB
    __shared__ float tw1s[NSMAX][6], tw2s[NSMAX][6];
    __shared__ int tslm[NSMAX];
    int tile = blockIdx.x;
    int TQ = tile / NT1, TU = tile - TQ * NT1;
    {   // stage: 21 rows x 63 uint4, fully coalesced
        const uint4* g4 = (const uint4*)Gpad;
        uint4* p4 = (uint4*)patch;
        int base = (TQ * TEDGE * GPAD + TU * TEDGE) * 3;   // uint4 index of patch row 0
        for (int i = threadIdx.x; i < PAT * 63; i += 256) {
            int r = i / 63, c = i - r * 63;
            p4[i] = g4[base + r * (GPAD * 3) + c];
        }
    }
    int end = offs[tile], ns = cnt[tile], start = end - ns;
    for (int s0 = 0; s0 < ns; s0 += NSMAX) {
        int nss = min(NSMAX, ns - s0);
        if ((int)threadIdx.x < nss) {           // taps once per sample
            int m = order[start + s0 + threadIdx.x];
            float fu, fq;
            int ibu = tapbase(kt[m], &fu);
            int ibq = tapbase(kt[MS + m], &fq);
            #pragma unroll
            for (int j = 0; j < 6; ++j) {
                tw1s[threadIdx.x][j] = kbval(fu + (float)(2 - j));
                tw2s[threadIdx.x][j] = kbval(fq + (float)(2 - j)) * GSC_INV;
            }
            tslm[threadIdx.x] = (m << 8) | ((ibu & 15) << 4) | (ibq & 15);
        }
        __syncthreads();                        // patch + taps ready
        for (int it = threadIdx.x; it < 3 * nss; it += 256) {
            int s = it / 3;
            int p = it - 3 * s;                 // coil quad 0..2
            int pk = tslm[s];
            int slq = pk & 15, slu = (pk >> 4) & 15, m = pk >> 8;
            float ar[4] = {0.f, 0.f, 0.f, 0.f}, ai[4] = {0.f, 0.f, 0.f, 0.f};
            #pragma unroll
            for (int j2 = 0; j2 < 6; ++j2) {
                int rowoff = (slq + j2) * PROW + slu * 12 + 4 * p;
                float b2 = tw2s[s][j2];
                #pragma unroll
                for (int j1 = 0; j1 < 6; ++j1) {
                    float4 gq = *(const float4*)&patch[rowoff + j1 * 12];
                    const __half2* h = (const __half2*)&gq;   // 4 x (re,im)
                    float ww = b2 * tw1s[s][j1];
                    #pragma unroll
                    for (int k = 0; k < 4; ++k) {
                        float2 fv = __half22float2(h[k]);
                        ar[k] = fmaf(ww, fv.x, ar[k]);
                        ai[k] = fmaf(ww, fv.y, ai[k]);
                    }
                }
            }
            #pragma unroll
            for (int k = 0; k < 4; ++k)
                out[(4 * p + k) * MS + m] = make_float2(ar[k], ai[k]);
        }
        __syncthreads();                        // before next chunk's tap overwrite
    }
}

extern "C" void kernel_launch(void* const* d_in, const int* in_sizes, int n_in,
                              void* d_out, int out_size, void* d_ws, size_t ws_size,
                              hipStream_t stream) {
    const float* img_r = (const float*)d_in[0];
    const float* img_i = (const float*)d_in[1];
    const float* sm_r  = (const float*)d_in[2];
    const float* sm_i  = (const float*)d_in[3];
    const float* kt    = (const float*)d_in[4];

    // ws layout (~30.2MB): [R16 9.83M][Gpad 19.97M][cnt 6.4K][offs 6.4K][order 0.41M]
    char* base = (char*)d_ws;
    unsigned int* R16  = (unsigned int*)base;                   // 12*320*640*4
    unsigned int* Gpad = (unsigned int*)(base + 9830400);       // 645*645*12*4
    int* cnt           = (int*)(base + 29799600);
    int* offs          = (int*)(base + 29806000);
    int* order         = (int*)(base + 29812400);

    hipMemsetAsync(cnt, 0, NTILES * sizeof(int), stream);
    passA_kernel<<<480, 512, 0, stream>>>(img_r, img_i, sm_r, sm_i, kt, cnt, R16);
    passB1G_kernel<<<GSZ, 512, 0, stream>>>(R16, cnt, offs, Gpad);
    binscatter_kernel<<<400, 256, 0, stream>>>(kt, offs, order);
    interp_tiled_kernel<<<NTILES, 256, 0, stream>>>(kt, Gpad, cnt, offs, order, (float2*)d_out);
}